// Round 2
// baseline (6075.984 us; speedup 1.0000x reference)
//
#include <hip/hip_runtime.h>
#include <math.h>

#define N_OBJ   2048
#define R_REL   1024
#define OBJ_DIM 4096
#define H       512
#define NREL    51
#define NCLS    151
#define NODE    53
#define CLS_K   (NODE*H)       /* 27136 */

__device__ __forceinline__ float sigmoidf_(float x){ return 1.0f/(1.0f+expf(-x)); }

struct EpiArgs {
  const float* msW;    // chunk-local [2*RC][1536]
  const float* Arel;   // global [R_REL][NREL]
  const float* b2;
  const float* zbuf;   // chunk-local
  float* hidden;       // chunk-local
  const float* ofW2;
  const float* vW2;
  const int* ri;
  int r0;
  int RC;
};

// C[m,n] = sum_k A[m,k]*W[n,k] (+bias[n]) with optional fused epilogues.
// M,N multiples of 64; K multiple of 16. m is chunk-local row.
template<int EPI>
__global__ __launch_bounds__(256)
void gemm_nt(const float* __restrict__ A, int lda,
             const float* __restrict__ W, int ldw,
             const float* __restrict__ bias,
             float* __restrict__ C, int ldc, int K,
             EpiArgs e)
{
  __shared__ float As[16][68];
  __shared__ float Ws[16][68];
  const int tid = threadIdx.x;
  const int bm = blockIdx.y*64;
  const int bn = blockIdx.x*64;
  const int ty = tid>>4, tx = tid&15;
  float acc[4][4] = {};
  for (int k0=0; k0<K; k0+=16){
#pragma unroll
    for (int q=0;q<4;q++){
      int ee = q*256+tid;
      int m = ee>>4, kk = ee&15;
      As[kk][m] = A[(size_t)(bm+m)*lda + (k0+kk)];
      Ws[kk][m] = W[(size_t)(bn+m)*ldw + (k0+kk)];
    }
    __syncthreads();
#pragma unroll
    for (int kk=0;kk<16;kk++){
      const float4 a4 = *(const float4*)(&As[kk][ty*4]);
      const float4 b4 = *(const float4*)(&Ws[kk][tx*4]);
      float av_[4] = {a4.x,a4.y,a4.z,a4.w};
      float bv_[4] = {b4.x,b4.y,b4.z,b4.w};
#pragma unroll
      for (int i=0;i<4;i++)
#pragma unroll
        for (int j=0;j<4;j++)
          acc[i][j] = fmaf(av_[i], bv_[j], acc[i][j]);
    }
    __syncthreads();
  }
#pragma unroll
  for (int i=0;i<4;i++){
    const int m = bm + ty*4 + i;
#pragma unroll
    for (int j=0;j<4;j++){
      const int n = bn + tx*4 + j;
      float val = acc[i][j];
      if (bias) val += bias[n];
      if (EPI==0){
        C[(size_t)m*ldc+n] = val;
      } else if (EPI==1){
        // GRU finish: hv = tanh(avW5 + b5 + (rv*flat@U5+u5b)); flat = (1-z)*flat + z*hv
        int r = m/NODE, t = m - r*NODE;
        float aw = (t<2) ? e.msW[(size_t)r*1536 + 1024 + n]
                         : e.Arel[(size_t)(e.r0+r)*NREL + (t-2)] * e.msW[(size_t)(e.RC+r)*1536 + 1024 + n];
        float hv = tanhf(aw + e.b2[n] + val);
        size_t idx = (size_t)m*H + n;
        float z = e.zbuf[idx];
        float f = e.hidden[idx];
        e.hidden[idx] = (1.0f-z)*f + z*hv;
      } else {
        // out layer: relu(flat@ow1 + inp@ow2 + out_b); inp-part gathered (original of/v)
        int r = m/NODE, t = m - r*NODE;
        int gr = e.r0 + r;
        const float* g = (t==0) ? e.ofW2 + (size_t)e.ri[gr*3+1]*H
                        : (t==1) ? e.ofW2 + (size_t)e.ri[gr*3+2]*H
                        :          e.vW2  + (size_t)gr*H;
        val += g[n];
        C[(size_t)m*ldc+n] = fmaxf(val, 0.0f);
      }
    }
  }
}

// copy obj_logits to out[0:309248], argmax(logits[:,1:])+1 -> preds (int + float out)
__global__ void argmax_copy_kernel(const float* __restrict__ logits, float* __restrict__ out, int* __restrict__ preds)
{
  const int i = blockIdx.x;
  const int lane = threadIdx.x; // 64
  for (int c=lane; c<NCLS; c+=64)
    out[(size_t)i*NCLS + c] = logits[(size_t)i*NCLS + c];
  float bv = -INFINITY; int bi = 0x7fffffff;
  for (int c=1+lane; c<NCLS; c+=64){
    float x = logits[(size_t)i*NCLS + c];
    if (x > bv){ bv = x; bi = c; }
  }
  for (int off=32; off; off>>=1){
    float ov = __shfl_down(bv, off);
    int   oi = __shfl_down(bi, off);
    if (ov > bv || (ov == bv && oi < bi)){ bv = ov; bi = oi; }
  }
  if (lane==0){
    preds[i] = bi;
    out[(size_t)N_OBJ*NCLS + i] = (float)bi;
  }
}

// Wcat rows [0:512)=W3eff, [512:1024)=W4eff, [1024:1536)=W5eff ; Weff = W[:, :512]+W[:, 512:]
__global__ void wcat_kernel(const float* __restrict__ e3w, const float* __restrict__ e4w,
                            const float* __restrict__ e5w, float* __restrict__ Wcat)
{
  const int total = 1536*512;
  for (int i = blockIdx.x*blockDim.x+threadIdx.x; i<total; i += gridDim.x*blockDim.x){
    int j = i>>9, k = i&511;
    int w = j>>9, n = j&511;
    const float* Wp = (w==0)? e3w : (w==1)? e4w : e5w;
    Wcat[i] = Wp[(size_t)n*1024 + k] + Wp[(size_t)n*1024 + 512 + k];
  }
}

// chunk: fill hidden_c for relations [r0, r0+RC)
__global__ void build_hidden_kernel(const float* __restrict__ of, const float* __restrict__ v,
                                    const int* __restrict__ ri, float* __restrict__ hidden,
                                    int r0, int total4)
{
  for (int i = blockIdx.x*blockDim.x+threadIdx.x; i<total4; i += gridDim.x*blockDim.x){
    int h4 = i & 127;
    int m = i >> 7;
    int r = m/NODE, t = m - r*NODE;
    int gr = r0 + r;
    const float* src = (t==0)? of + (size_t)ri[gr*3+1]*H
                     : (t==1)? of + (size_t)ri[gr*3+2]*H
                     :         v  + (size_t)gr*H;
    ((float4*)hidden)[i] = ((const float4*)src)[h4];
  }
}

__global__ void arel_kernel(const int* __restrict__ preds, const int* __restrict__ ri,
                            const float* __restrict__ prior, float* __restrict__ Arel)
{
  const int total = R_REL*NREL;
  for (int i = blockIdx.x*blockDim.x+threadIdx.x; i<total; i += gridDim.x*blockDim.x){
    int r = i/NREL, k = i - r*NREL;
    int sp = preds[ri[r*3+1]];
    int op = preds[ri[r*3+2]];
    Arel[i] = prior[((size_t)sp*NCLS + op)*NREL + k];
  }
}

// X rows [0:RC) = m_top, [RC:2RC) = s = h0+h1  (chunk-local hidden)
__global__ void mtop_s_kernel(const float* __restrict__ hidden, const float* __restrict__ Arel,
                              float* __restrict__ X, int r0, int RC)
{
  const int r = blockIdx.x;  // local
  for (int h = threadIdx.x; h < H; h += blockDim.x){
    const float* base = hidden + ((size_t)r*NODE + 2)*H + h;
    float acc = 0.f;
    for (int k=0;k<NREL;k++)
      acc = fmaf(Arel[(size_t)(r0+r)*NREL+k], base[(size_t)k*H], acc);
    X[(size_t)r*H + h] = acc;
    X[(size_t)(RC + r)*H + h] = hidden[(size_t)(r*NODE)*H + h] + hidden[(size_t)(r*NODE+1)*H + h];
  }
}

// z = sigmoid(avW3+b3+U3) -> zb (in place over U3); rvf = sigmoid(avW4+b4+U3)*flat
__global__ void e1_kernel(const float* U3,
                          const float* __restrict__ hidden,
                          const float* __restrict__ msW,
                          const float* __restrict__ Arel,
                          const float* __restrict__ b3,
                          const float* __restrict__ b4,
                          float* zb,
                          float* __restrict__ rvf,
                          int r0, int RC, int total4)
{
  for (int i = blockIdx.x*blockDim.x+threadIdx.x; i<total4; i += gridDim.x*blockDim.x){
    int h4 = i & 127;
    int m = i >> 7;
    int r = m/NODE, t = m - r*NODE;
    float a; const float* mrow;
    if (t<2){ a = 1.0f; mrow = msW + (size_t)r*1536; }
    else    { a = Arel[(size_t)(r0+r)*NREL + (t-2)]; mrow = msW + (size_t)(RC + r)*1536; }
    int h = h4*4;
    float4 w3 = *(const float4*)(mrow + h);
    float4 w4 = *(const float4*)(mrow + 512 + h);
    float4 u  = ((const float4*)U3)[i];
    float4 f  = ((const float4*)hidden)[i];
    float4 vb3 = *(const float4*)(b3+h);
    float4 vb4 = *(const float4*)(b4+h);
    float4 z, rv, o;
    z.x = sigmoidf_(fmaf(a,w3.x,vb3.x) + u.x);
    z.y = sigmoidf_(fmaf(a,w3.y,vb3.y) + u.y);
    z.z = sigmoidf_(fmaf(a,w3.z,vb3.z) + u.z);
    z.w = sigmoidf_(fmaf(a,w3.w,vb3.w) + u.w);
    rv.x = sigmoidf_(fmaf(a,w4.x,vb4.x) + u.x);
    rv.y = sigmoidf_(fmaf(a,w4.y,vb4.y) + u.y);
    rv.z = sigmoidf_(fmaf(a,w4.z,vb4.z) + u.z);
    rv.w = sigmoidf_(fmaf(a,w4.w,vb4.w) + u.w);
    o.x = rv.x*f.x; o.y = rv.y*f.y; o.z = rv.z*f.z; o.w = rv.w*f.w;
    ((float4*)zb)[i] = z;
    ((float4*)rvf)[i] = o;
  }
}

// rel_dists[r0+rb+row, c] = sum_k outb[local,k]*clsw[c,k] + clsb[c]
__global__ __launch_bounds__(256)
void cls_kernel(const float* __restrict__ outb, const float* __restrict__ clsw,
                const float* __restrict__ clsb, float* __restrict__ rd, int r0)
{
  __shared__ float so[4][256];
  __shared__ float sc[51][257];
  const int lr0 = blockIdx.x*4;
  const int tid = threadIdx.x;
  const int row = tid/51, c = tid%51;  // valid when tid<204
  float acc = 0.f;
  for (int k0=0; k0<CLS_K; k0+=256){
#pragma unroll
    for (int q=0;q<4;q++)
      so[q][tid] = outb[(size_t)(lr0+q)*CLS_K + k0 + tid];
    for (int cc=0; cc<51; cc++)
      sc[cc][tid] = clsw[(size_t)cc*CLS_K + k0 + tid];
    __syncthreads();
    if (tid < 204){
#pragma unroll 8
      for (int k=0;k<256;k++)
        acc = fmaf(so[row][k], sc[c][k], acc);
    }
    __syncthreads();
  }
  if (tid < 204)
    rd[(size_t)(r0+lr0+row)*NREL + c] = acc + clsb[c];
}

extern "C" void kernel_launch(void* const* d_in, const int* in_sizes, int n_in,
                              void* d_out, int out_size, void* d_ws, size_t ws_size,
                              hipStream_t stream)
{
  const float* obj_fmaps = (const float*)d_in[0];
  const float* obj_logits= (const float*)d_in[1];
  const int*   rel_inds  = (const int*)d_in[2];
  const float* vr        = (const float*)d_in[3];
  const float* prior     = (const float*)d_in[4];
  const float* obj_proj_w= (const float*)d_in[5];
  const float* obj_proj_b= (const float*)d_in[6];
  const float* rel_proj_w= (const float*)d_in[7];
  const float* rel_proj_b= (const float*)d_in[8];
  const float* e3w =(const float*)d_in[9];
  const float* e3wb=(const float*)d_in[10];
  const float* e3u =(const float*)d_in[11];
  const float* e3ub=(const float*)d_in[12];
  const float* e4w =(const float*)d_in[13];
  const float* e4wb=(const float*)d_in[14];
  const float* e5w =(const float*)d_in[15];
  const float* e5wb=(const float*)d_in[16];
  const float* e5u =(const float*)d_in[17];
  const float* e5ub=(const float*)d_in[18];
  const float* outw=(const float*)d_in[19];
  const float* outbias=(const float*)d_in[20];
  const float* clsw=(const float*)d_in[21];
  const float* clsb=(const float*)d_in[22];
  float* out = (float*)d_out;
  (void)in_sizes; (void)n_in; (void)out_size;

  // runtime chunk size from ws_size (deterministic per session -> capture safe)
  const size_t fixed_fl = (size_t)N_OBJ*H + (size_t)R_REL*H + (size_t)N_OBJ*H + (size_t)R_REL*H
                        + 3*512*512 + (size_t)R_REL*NREL + 2048;
  int RC = 256;  // cap: ~104 MB total
  while (RC > 64) {
    size_t per_fl = (size_t)RC*(2*512 + 2*1536 + 3*NODE*512);
    if ((fixed_fl + per_fl)*sizeof(float) <= ws_size) break;
    RC >>= 1;
  }
  const int NCH = R_REL / RC;
  const int M_c = RC*NODE;          // multiple of 64 (RC multiple of 64, 53*64 blocks)
  const int total4 = M_c*(H/4);

  float* ws = (float*)d_ws;
  size_t off = 0;
  auto alloc = [&](size_t n){ float* p = ws + off; off += n; return p; };
  float* of     = alloc((size_t)N_OBJ*H);
  float* v      = alloc((size_t)R_REL*H);
  float* ofW2   = alloc((size_t)N_OBJ*H);
  float* vW2    = alloc((size_t)R_REL*H);
  float* Wcat   = alloc((size_t)3*512*512);
  float* Arel   = alloc((size_t)R_REL*NREL);
  int*   preds  = (int*)alloc(2048);
  float* X_c    = alloc((size_t)2*RC*H);
  float* msW_c  = alloc((size_t)2*RC*1536);
  float* hid_c  = alloc((size_t)M_c*H);
  float* U3_c   = alloc((size_t)M_c*H);
  float* rvf_c  = alloc((size_t)M_c*H);   // also reused as out-layer activations

  EpiArgs e0{};

  argmax_copy_kernel<<<N_OBJ, 64, 0, stream>>>(obj_logits, out, preds);

  gemm_nt<0><<<dim3(H/64, N_OBJ/64), 256, 0, stream>>>(obj_fmaps, OBJ_DIM, obj_proj_w, OBJ_DIM, obj_proj_b, of, H, OBJ_DIM, e0);
  gemm_nt<0><<<dim3(H/64, R_REL/64), 256, 0, stream>>>(vr, OBJ_DIM, rel_proj_w, OBJ_DIM, rel_proj_b, v, H, OBJ_DIM, e0);

  wcat_kernel<<<768, 256, 0, stream>>>(e3w, e4w, e5w, Wcat);
  arel_kernel<<<204, 256, 0, stream>>>(preds, rel_inds, prior, Arel);

  // loop-invariant out-layer inp-part projections (use ORIGINAL of/v)
  gemm_nt<0><<<dim3(H/64, N_OBJ/64), 256, 0, stream>>>(of, H, outw+512, 1024, nullptr, ofW2, H, H, e0);
  gemm_nt<0><<<dim3(H/64, R_REL/64), 256, 0, stream>>>(v, H, outw+512, 1024, nullptr, vW2, H, H, e0);

  float* rd = out + (size_t)N_OBJ*NCLS + N_OBJ;

  for (int c=0; c<NCH; ++c){
    const int r0 = c*RC;
    build_hidden_kernel<<<2048, 256, 0, stream>>>(of, v, rel_inds, hid_c, r0, total4);

    for (int step=0; step<3; ++step){
      mtop_s_kernel<<<RC, 256, 0, stream>>>(hid_c, Arel, X_c, r0, RC);
      gemm_nt<0><<<dim3(1536/64, 2*RC/64), 256, 0, stream>>>(X_c, H, Wcat, H, nullptr, msW_c, 1536, H, e0);
      gemm_nt<0><<<dim3(H/64, M_c/64), 256, 0, stream>>>(hid_c, H, e3u, H, e3ub, U3_c, H, H, e0);
      e1_kernel<<<2048, 256, 0, stream>>>(U3_c, hid_c, msW_c, Arel, e3wb, e4wb, U3_c, rvf_c, r0, RC, total4);
      EpiArgs e1a{};
      e1a.msW = msW_c; e1a.Arel = Arel; e1a.b2 = e5wb; e1a.zbuf = U3_c; e1a.hidden = hid_c;
      e1a.r0 = r0; e1a.RC = RC;
      gemm_nt<1><<<dim3(H/64, M_c/64), 256, 0, stream>>>(rvf_c, H, e5u, H, e5ub, hid_c, H, H, e1a);
    }

    EpiArgs e2a{};
    e2a.ofW2 = ofW2; e2a.vW2 = vW2; e2a.ri = rel_inds; e2a.r0 = r0; e2a.RC = RC;
    gemm_nt<2><<<dim3(H/64, M_c/64), 256, 0, stream>>>(hid_c, H, outw, 1024, outbias, rvf_c, H, H, e2a);

    cls_kernel<<<RC/4, 256, 0, stream>>>(rvf_c, clsw, clsb, rd, r0);
  }
}

// Round 3
// 2406.699 us; speedup vs baseline: 2.5246x; 2.5246x over previous
//
#include <hip/hip_runtime.h>
#include <math.h>

#define N_OBJ   2048
#define R_REL   1024
#define OBJ_DIM 4096
#define H       512
#define NREL    51
#define NCLS    151
#define NODE    53
#define CLS_K   (NODE*H)       /* 27136 */

typedef unsigned short u16;
typedef __attribute__((ext_vector_type(8))) short bf16x8;
typedef __attribute__((ext_vector_type(4))) float f32x4;

__device__ __forceinline__ float sigmoidf_(float x){ return 1.0f/(1.0f+expf(-x)); }
__device__ __forceinline__ u16 f2bf(float x){
  unsigned u = __float_as_uint(x);
  unsigned r = (u + 0x7fffu + ((u>>16)&1u)) >> 16;
  return (u16)r;
}
__device__ __forceinline__ float bf2f(u16 h){ return __uint_as_float(((unsigned)h)<<16); }

struct EpiArgs {
  const float* msW;      // [2*RC][1536]
  const float* Arel;     // [R_REL][NREL]
  const float* b2;       // e5wb
  const float* b3;       // e3wb
  const float* b4;       // e4wb
  const u16*   hid_bf_r;
  u16*         z_bf;
  u16*         rvf_bf;
  float*       hidden;   // f32 hidden (EPI1 update)
  u16*         hid_bf_w;
  const float* ofW2;
  const float* vW2;
  const int*   ri;
  u16*         cbf;      // secondary bf16 output (EPI2/EPI4)
  int r0;
  int RC;
};

// C[m,n] = sum_k A[m,k]*B[n,k] (+bias[n]); A[M][lda], B[N][ldb] bf16 row-major.
// BM=BN=128, BK=32; 4 waves (2x2), each wave 64x64 via 4x4 MFMA 16x16x32 frags.
// EPI: 0 = f32 store; 1 = GRU finish; 2 = out-layer relu->bf16; 3 = fused e1; 4 = f32+bf16 dual store
template<int EPI>
__global__ __launch_bounds__(256)
void gemm_bf16(const u16* __restrict__ A, int lda,
               const u16* __restrict__ B, int ldb,
               const float* __restrict__ bias,
               float* __restrict__ C, int ldc, int K, EpiArgs e)
{
  __shared__ __align__(16) u16 As[128*40];   // row stride 40 elems (80B) -> conflict-free-ish
  __shared__ __align__(16) u16 Bs[128*40];
  const int tid = threadIdx.x;
  const int l   = tid & 63;
  const int wid = tid >> 6;
  const int wm  = wid >> 1, wn = wid & 1;
  const int bm  = blockIdx.y*128, bn = blockIdx.x*128;
  const int lr  = l & 15, q = l >> 4;

  f32x4 acc[4][4] = {};

  for (int k0 = 0; k0 < K; k0 += 32){
#pragma unroll
    for (int p = 0; p < 2; ++p){
      int idx = p*256 + tid;          // 0..511
      int row = idx >> 2;             // 0..127
      int c8  = (idx & 3) * 8;        // 0,8,16,24
      *(uint4*)&As[row*40 + c8] = *(const uint4*)&A[(size_t)(bm+row)*lda + k0 + c8];
      *(uint4*)&Bs[row*40 + c8] = *(const uint4*)&B[(size_t)(bn+row)*ldb + k0 + c8];
    }
    __syncthreads();
    bf16x8 af[4], bfr[4];
#pragma unroll
    for (int i = 0; i < 4; ++i)
      af[i] = *(const bf16x8*)&As[(wm*64 + i*16 + lr)*40 + q*8];
#pragma unroll
    for (int i = 0; i < 4; ++i)
      bfr[i] = *(const bf16x8*)&Bs[(wn*64 + i*16 + lr)*40 + q*8];
#pragma unroll
    for (int mi = 0; mi < 4; ++mi)
#pragma unroll
      for (int ni = 0; ni < 4; ++ni)
        acc[mi][ni] = __builtin_amdgcn_mfma_f32_16x16x32_bf16(af[mi], bfr[ni], acc[mi][ni], 0, 0, 0);
    __syncthreads();
  }

#pragma unroll
  for (int mi = 0; mi < 4; ++mi){
#pragma unroll
    for (int ni = 0; ni < 4; ++ni){
#pragma unroll
      for (int i = 0; i < 4; ++i){
        const int m = bm + wm*64 + mi*16 + q*4 + i;   // row = (lane>>4)*4 + reg
        const int n = bn + wn*64 + ni*16 + lr;        // col = lane&15
        float val = acc[mi][ni][i];
        if (bias) val += bias[n];
        if (EPI == 0){
          C[(size_t)m*ldc + n] = val;
        } else if (EPI == 4){
          C[(size_t)m*ldc + n] = val;
          e.cbf[(size_t)m*ldc + n] = f2bf(val);
        } else if (EPI == 3){
          // fused e1: val = flat@U3 + e3ub ; z/rv sigmoids ; rvf = rv*flat
          int r = m/NODE, t = m - r*NODE;
          float a; const float* mrow;
          if (t < 2){ a = 1.0f; mrow = e.msW + (size_t)r*1536; }
          else { a = e.Arel[(size_t)(e.r0+r)*NREL + (t-2)]; mrow = e.msW + (size_t)(e.RC + r)*1536; }
          float z  = sigmoidf_(fmaf(a, mrow[n],       e.b3[n]) + val);
          float rv = sigmoidf_(fmaf(a, mrow[512 + n], e.b4[n]) + val);
          size_t idx = (size_t)m*H + n;
          float f = bf2f(e.hid_bf_r[idx]);
          e.z_bf[idx]   = f2bf(z);
          e.rvf_bf[idx] = f2bf(rv*f);
        } else if (EPI == 1){
          // GRU finish: hv = tanh(av@W5eff + e5wb + val); flat = (1-z)f + z*hv
          int r = m/NODE, t = m - r*NODE;
          float aw = (t < 2) ? e.msW[(size_t)r*1536 + 1024 + n]
                             : e.Arel[(size_t)(e.r0+r)*NREL + (t-2)] * e.msW[(size_t)(e.RC + r)*1536 + 1024 + n];
          float hv = tanhf(aw + e.b2[n] + val);
          size_t idx = (size_t)m*H + n;
          float z = bf2f(e.z_bf[idx]);
          float f = e.hidden[idx];
          float nf = (1.0f - z)*f + z*hv;
          e.hidden[idx] = nf;
          e.hid_bf_w[idx] = f2bf(nf);
        } else {
          // EPI 2: out layer relu(flat@ow1 + inp@ow2 + out_b) -> bf16
          int r = m/NODE, t = m - r*NODE;
          int gr = e.r0 + r;
          const float* g = (t == 0) ? e.ofW2 + (size_t)e.ri[gr*3+1]*H
                         : (t == 1) ? e.ofW2 + (size_t)e.ri[gr*3+2]*H
                         :            e.vW2  + (size_t)gr*H;
          e.cbf[(size_t)m*H + n] = f2bf(fmaxf(val + g[n], 0.0f));
        }
      }
    }
  }
}

// classifier: partials[kz][m][n] = sum over K-slice kz of A[m,:] . B[n,:]
// A = outact_bf [RC][27136], B = clsw_bf [64][27136]. grid (RC/64, 16), 1 wave.
__global__ __launch_bounds__(64)
void cls_gemm(const u16* __restrict__ A, const u16* __restrict__ B,
              float* __restrict__ part, int RC)
{
  const int bm = blockIdx.x*64;
  const int kz = blockIdx.y;
  const int l  = threadIdx.x;
  const int lr = l & 15, q = l >> 4;
  f32x4 acc[4][4] = {};
  const size_t kbase = (size_t)kz*1696 + q*8;
  for (int kt = 0; kt < 53; ++kt){
    const size_t ko = kbase + (size_t)kt*32;
    bf16x8 af[4], bfr[4];
#pragma unroll
    for (int i = 0; i < 4; ++i)
      af[i] = *(const bf16x8*)&A[(size_t)(bm + i*16 + lr)*CLS_K + ko];
#pragma unroll
    for (int i = 0; i < 4; ++i)
      bfr[i] = *(const bf16x8*)&B[(size_t)(i*16 + lr)*CLS_K + ko];
#pragma unroll
    for (int mi = 0; mi < 4; ++mi)
#pragma unroll
      for (int ni = 0; ni < 4; ++ni)
        acc[mi][ni] = __builtin_amdgcn_mfma_f32_16x16x32_bf16(af[mi], bfr[ni], acc[mi][ni], 0, 0, 0);
  }
#pragma unroll
  for (int mi = 0; mi < 4; ++mi)
#pragma unroll
    for (int ni = 0; ni < 4; ++ni)
#pragma unroll
      for (int i = 0; i < 4; ++i){
        int m = bm + mi*16 + q*4 + i;
        int n = ni*16 + lr;
        part[((size_t)kz*RC + m)*64 + n] = acc[mi][ni][i];
      }
}

__global__ void cls_reduce(const float* __restrict__ part, const float* __restrict__ clsb,
                           float* __restrict__ rd, int r0, int RC)
{
  const int m = blockIdx.x;
  const int c = threadIdx.x;
  if (c < NREL){
    float s = clsb[c];
    for (int kz = 0; kz < 16; ++kz) s += part[((size_t)kz*RC + m)*64 + c];
    rd[(size_t)(r0 + m)*NREL + c] = s;
  }
}

__global__ void argmax_copy_kernel(const float* __restrict__ logits, float* __restrict__ out, int* __restrict__ preds)
{
  const int i = blockIdx.x;
  const int lane = threadIdx.x; // 64
  for (int c = lane; c < NCLS; c += 64)
    out[(size_t)i*NCLS + c] = logits[(size_t)i*NCLS + c];
  float bv = -INFINITY; int bi = 0x7fffffff;
  for (int c = 1 + lane; c < NCLS; c += 64){
    float x = logits[(size_t)i*NCLS + c];
    if (x > bv){ bv = x; bi = c; }
  }
  for (int off = 32; off; off >>= 1){
    float ov = __shfl_down(bv, off);
    int   oi = __shfl_down(bi, off);
    if (ov > bv || (ov == bv && oi < bi)){ bv = ov; bi = oi; }
  }
  if (lane == 0){
    preds[i] = bi;
    out[(size_t)N_OBJ*NCLS + i] = (float)bi;
  }
}

__global__ void conv_f2b(const float* __restrict__ s, u16* __restrict__ d, long n)
{
  for (long i = (long)blockIdx.x*blockDim.x + threadIdx.x; i < n; i += (long)gridDim.x*blockDim.x)
    d[i] = f2bf(s[i]);
}

__global__ void conv_ow(const float* __restrict__ src, u16* __restrict__ d1, u16* __restrict__ d2)
{
  for (int i = blockIdx.x*blockDim.x + threadIdx.x; i < 512*512; i += gridDim.x*blockDim.x){
    int r = i >> 9, c = i & 511;
    d1[i] = f2bf(src[(size_t)r*1024 + c]);
    d2[i] = f2bf(src[(size_t)r*1024 + 512 + c]);
  }
}

__global__ void conv_cls(const float* __restrict__ src, u16* __restrict__ dst)
{
  const long total = 64L*CLS_K;
  for (long i = (long)blockIdx.x*blockDim.x + threadIdx.x; i < total; i += (long)gridDim.x*blockDim.x){
    long r = i / CLS_K, c = i - r*CLS_K;
    dst[i] = (r < NREL) ? f2bf(src[(size_t)r*CLS_K + c]) : (u16)0;
  }
}

// Wcat_bf rows [0:512)=W3eff, [512:1024)=W4eff, [1024:1536)=W5eff ; Weff = W[:,:512]+W[:,512:]
__global__ void wcat_kernel(const float* __restrict__ e3w, const float* __restrict__ e4w,
                            const float* __restrict__ e5w, u16* __restrict__ Wcat)
{
  const int total = 1536*512;
  for (int i = blockIdx.x*blockDim.x + threadIdx.x; i < total; i += gridDim.x*blockDim.x){
    int j = i >> 9, k = i & 511;
    int w = j >> 9, n = j & 511;
    const float* Wp = (w == 0) ? e3w : (w == 1) ? e4w : e5w;
    Wcat[i] = f2bf(Wp[(size_t)n*1024 + k] + Wp[(size_t)n*1024 + 512 + k]);
  }
}

__global__ void build_hidden_kernel(const float* __restrict__ of, const float* __restrict__ v,
                                    const int* __restrict__ ri, float* __restrict__ hidden,
                                    u16* __restrict__ hid_bf, int r0, int total4)
{
  for (int i = blockIdx.x*blockDim.x + threadIdx.x; i < total4; i += gridDim.x*blockDim.x){
    int h4 = i & 127;
    int m = i >> 7;
    int r = m/NODE, t = m - r*NODE;
    int gr = r0 + r;
    const float* src = (t == 0) ? of + (size_t)ri[gr*3+1]*H
                     : (t == 1) ? of + (size_t)ri[gr*3+2]*H
                     :            v  + (size_t)gr*H;
    float4 val = ((const float4*)src)[h4];
    ((float4*)hidden)[i] = val;
    ushort4 hb; hb.x = f2bf(val.x); hb.y = f2bf(val.y); hb.z = f2bf(val.z); hb.w = f2bf(val.w);
    ((ushort4*)hid_bf)[i] = hb;
  }
}

__global__ void arel_kernel(const int* __restrict__ preds, const int* __restrict__ ri,
                            const float* __restrict__ prior, float* __restrict__ Arel)
{
  const int total = R_REL*NREL;
  for (int i = blockIdx.x*blockDim.x + threadIdx.x; i < total; i += gridDim.x*blockDim.x){
    int r = i/NREL, k = i - r*NREL;
    int sp = preds[ri[r*3+1]];
    int op = preds[ri[r*3+2]];
    Arel[i] = prior[((size_t)sp*NCLS + op)*NREL + k];
  }
}

// X rows [0:RC) = m_top (bf16), [RC:2RC) = h0+h1 (bf16)
__global__ void mtop_s_kernel(const float* __restrict__ hidden, const float* __restrict__ Arel,
                              u16* __restrict__ X, int r0, int RC)
{
  const int r = blockIdx.x;
  for (int h = threadIdx.x; h < H; h += blockDim.x){
    const float* base = hidden + ((size_t)r*NODE + 2)*H + h;
    float acc = 0.f;
    for (int k = 0; k < NREL; ++k)
      acc = fmaf(Arel[(size_t)(r0+r)*NREL + k], base[(size_t)k*H], acc);
    X[(size_t)r*H + h] = f2bf(acc);
    X[(size_t)(RC + r)*H + h] = f2bf(hidden[(size_t)(r*NODE)*H + h] + hidden[(size_t)(r*NODE+1)*H + h]);
  }
}

extern "C" void kernel_launch(void* const* d_in, const int* in_sizes, int n_in,
                              void* d_out, int out_size, void* d_ws, size_t ws_size,
                              hipStream_t stream)
{
  const float* obj_fmaps = (const float*)d_in[0];
  const float* obj_logits= (const float*)d_in[1];
  const int*   rel_inds  = (const int*)d_in[2];
  const float* vr        = (const float*)d_in[3];
  const float* prior     = (const float*)d_in[4];
  const float* obj_proj_w= (const float*)d_in[5];
  const float* obj_proj_b= (const float*)d_in[6];
  const float* rel_proj_w= (const float*)d_in[7];
  const float* rel_proj_b= (const float*)d_in[8];
  const float* e3w =(const float*)d_in[9];
  const float* e3wb=(const float*)d_in[10];
  const float* e3u =(const float*)d_in[11];
  const float* e3ub=(const float*)d_in[12];
  const float* e4w =(const float*)d_in[13];
  const float* e4wb=(const float*)d_in[14];
  const float* e5w =(const float*)d_in[15];
  const float* e5wb=(const float*)d_in[16];
  const float* e5u =(const float*)d_in[17];
  const float* e5ub=(const float*)d_in[18];
  const float* outw=(const float*)d_in[19];
  const float* outbias=(const float*)d_in[20];
  const float* clsw=(const float*)d_in[21];
  const float* clsb=(const float*)d_in[22];
  float* out = (float*)d_out;
  (void)in_sizes; (void)n_in; (void)out_size;

  char* base = (char*)d_ws;
  size_t off = 0;
  auto take = [&](size_t bytes)->void*{
    void* p = base + off; off = (off + bytes + 15) & ~(size_t)15; return p;
  };
  // persistent
  float* of     = (float*)take((size_t)N_OBJ*H*4);
  float* v      = (float*)take((size_t)R_REL*H*4);
  float* ofW2   = (float*)take((size_t)N_OBJ*H*4);
  float* vW2    = (float*)take((size_t)R_REL*H*4);
  float* Arel   = (float*)take((size_t)R_REL*NREL*4);
  int*   preds  = (int*)take((size_t)N_OBJ*4);
  u16* opw_bf   = (u16*)take((size_t)H*OBJ_DIM*2);
  u16* rpw_bf   = (u16*)take((size_t)H*OBJ_DIM*2);
  u16* e3u_bf   = (u16*)take((size_t)H*H*2);
  u16* e5u_bf   = (u16*)take((size_t)H*H*2);
  u16* ow1_bf   = (u16*)take((size_t)H*H*2);
  u16* ow2_bf   = (u16*)take((size_t)H*H*2);
  u16* wcat_bf  = (u16*)take((size_t)1536*H*2);
  u16* clsw_bf  = (u16*)take((size_t)64*CLS_K*2);
  u16* of_bf    = (u16*)take((size_t)N_OBJ*H*2);
  u16* v_bf     = (u16*)take((size_t)R_REL*H*2);
  const size_t mark = off;

  // union region A: input bf16 conversions (only live before the chunk loop)
  u16* fmaps_bf = (u16*)(base + mark);
  u16* vr_bf    = fmaps_bf + (size_t)N_OBJ*OBJ_DIM;
  const size_t unionA = ((size_t)N_OBJ*OBJ_DIM + (size_t)R_REL*OBJ_DIM)*2;

  auto perbytes = [&](int rc)->size_t{
    size_t b = 0;
    b += (size_t)rc*NODE*H*4;       // hid_c f32
    b += (size_t)2*rc*1536*4;       // msW f32
    b += (size_t)16*rc*64*4;        // cls partials
    b += (size_t)rc*NODE*H*2*3;     // hid_bf, z_bf, rvf_bf
    b += (size_t)2*rc*H*2;          // X_bf
    b += 256;                       // align slack
    return b;
  };
  int RC = 256;
  {
    size_t need256 = mark + (perbytes(256) > unionA ? perbytes(256) : unionA);
    if (need256 > ws_size) RC = 128;
  }
  const int NCH = R_REL / RC;
  const int M_c = RC*NODE;
  const int total4 = M_c*(H/4);

  off = mark;
  float* hid_c   = (float*)take((size_t)M_c*H*4);
  float* msW_c   = (float*)take((size_t)2*RC*1536*4);
  float* clspart = (float*)take((size_t)16*RC*64*4);
  u16* hid_bf    = (u16*)take((size_t)M_c*H*2);
  u16* z_bf      = (u16*)take((size_t)M_c*H*2);
  u16* rvf_bf    = (u16*)take((size_t)M_c*H*2);   // aliased as outact_bf after last step
  u16* X_bf      = (u16*)take((size_t)2*RC*H*2);

  EpiArgs e0{};

  argmax_copy_kernel<<<N_OBJ, 64, 0, stream>>>(obj_logits, out, preds);

  // conversions
  conv_f2b<<<2048, 256, 0, stream>>>(obj_fmaps, fmaps_bf, (long)N_OBJ*OBJ_DIM);
  conv_f2b<<<2048, 256, 0, stream>>>(vr, vr_bf, (long)R_REL*OBJ_DIM);
  conv_f2b<<<1024, 256, 0, stream>>>(obj_proj_w, opw_bf, (long)H*OBJ_DIM);
  conv_f2b<<<1024, 256, 0, stream>>>(rel_proj_w, rpw_bf, (long)H*OBJ_DIM);
  conv_f2b<<<256, 256, 0, stream>>>(e3u, e3u_bf, (long)H*H);
  conv_f2b<<<256, 256, 0, stream>>>(e5u, e5u_bf, (long)H*H);
  conv_ow<<<256, 256, 0, stream>>>(outw, ow1_bf, ow2_bf);
  conv_cls<<<2048, 256, 0, stream>>>(clsw, clsw_bf);
  wcat_kernel<<<768, 256, 0, stream>>>(e3w, e4w, e5w, wcat_bf);
  arel_kernel<<<204, 256, 0, stream>>>(preds, rel_inds, prior, Arel);

  // projections (dual f32+bf16 outputs)
  { EpiArgs e = e0; e.cbf = of_bf;
    gemm_bf16<4><<<dim3(H/128, N_OBJ/128), 256, 0, stream>>>(fmaps_bf, OBJ_DIM, opw_bf, OBJ_DIM, obj_proj_b, of, H, OBJ_DIM, e); }
  { EpiArgs e = e0; e.cbf = v_bf;
    gemm_bf16<4><<<dim3(H/128, R_REL/128), 256, 0, stream>>>(vr_bf, OBJ_DIM, rpw_bf, OBJ_DIM, rel_proj_b, v, H, OBJ_DIM, e); }

  // loop-invariant out-layer inp-part projections
  gemm_bf16<0><<<dim3(H/128, N_OBJ/128), 256, 0, stream>>>(of_bf, H, ow2_bf, H, nullptr, ofW2, H, H, e0);
  gemm_bf16<0><<<dim3(H/128, R_REL/128), 256, 0, stream>>>(v_bf, H, ow2_bf, H, nullptr, vW2, H, H, e0);

  float* rd = out + (size_t)N_OBJ*NCLS + N_OBJ;

  for (int c = 0; c < NCH; ++c){
    const int r0 = c*RC;
    build_hidden_kernel<<<2048, 256, 0, stream>>>(of, v, rel_inds, hid_c, hid_bf, r0, total4);

    for (int step = 0; step < 3; ++step){
      mtop_s_kernel<<<RC, 256, 0, stream>>>(hid_c, Arel, X_bf, r0, RC);
      gemm_bf16<0><<<dim3(1536/128, 2*RC/128), 256, 0, stream>>>(X_bf, H, wcat_bf, H, nullptr, msW_c, 1536, H, e0);
      { EpiArgs e = e0;
        e.msW = msW_c; e.Arel = Arel; e.b3 = e3wb; e.b4 = e4wb;
        e.hid_bf_r = hid_bf; e.z_bf = z_bf; e.rvf_bf = rvf_bf; e.r0 = r0; e.RC = RC;
        gemm_bf16<3><<<dim3(H/128, M_c/128), 256, 0, stream>>>(hid_bf, H, e3u_bf, H, e3ub, nullptr, 0, H, e); }
      { EpiArgs e = e0;
        e.msW = msW_c; e.Arel = Arel; e.b2 = e5wb; e.z_bf = z_bf;
        e.hidden = hid_c; e.hid_bf_w = hid_bf; e.r0 = r0; e.RC = RC;
        gemm_bf16<1><<<dim3(H/128, M_c/128), 256, 0, stream>>>(rvf_bf, H, e5u_bf, H, e5ub, nullptr, 0, H, e); }
    }

    { EpiArgs e = e0;
      e.ofW2 = ofW2; e.vW2 = vW2; e.ri = rel_inds; e.cbf = rvf_bf; e.r0 = r0; e.RC = RC;
      gemm_bf16<2><<<dim3(H/128, M_c/128), 256, 0, stream>>>(hid_bf, H, ow1_bf, H, outbias, nullptr, 0, H, e); }

    cls_gemm<<<dim3(RC/64, 16), 64, 0, stream>>>(rvf_bf, clsw_bf, clspart, RC);
    cls_reduce<<<RC, 64, 0, stream>>>(clspart, clsb, rd, r0, RC);
  }
}

// Round 4
// 1659.713 us; speedup vs baseline: 3.6609x; 1.4501x over previous
//
#include <hip/hip_runtime.h>
#include <math.h>

#define N_OBJ   2048
#define R_REL   1024
#define OBJ_DIM 4096
#define H       512
#define NREL    51
#define NCLS    151
#define NODE    53
#define CLS_K   (NODE*H)       /* 27136 */

typedef unsigned short u16;
typedef __attribute__((ext_vector_type(8))) short bf16x8;
typedef __attribute__((ext_vector_type(4))) float f32x4;

__device__ __forceinline__ float sigmoidf_(float x){ return 1.0f/(1.0f+expf(-x)); }
__device__ __forceinline__ u16 f2bf(float x){
  unsigned u = __float_as_uint(x);
  unsigned r = (u + 0x7fffu + ((u>>16)&1u)) >> 16;
  return (u16)r;
}
__device__ __forceinline__ float bf2f(u16 h){ return __uint_as_float(((unsigned)h)<<16); }

// direct global->LDS DMA, 16B per lane; LDS dest = wave-uniform base + lane*16
#define GLL16(gp, lp) __builtin_amdgcn_global_load_lds( \
    (const __attribute__((address_space(1))) void*)(gp), \
    (__attribute__((address_space(3))) void*)(lp), 16, 0, 0)

struct EpiArgs {
  const u16*   msW;      // bf16 [2*RC][1536]
  const float* Arel;     // [R_REL][NREL]
  const float* b2;       // e5wb
  const float* b3;       // e3wb
  const float* b4;       // e4wb
  const u16*   hid_r;    // bf16 hidden (read)
  u16*         z_bf;
  u16*         rvf_bf;
  u16*         hid_w;    // bf16 hidden (write, EPI1)
  const float* ofW2;
  const float* vW2;
  const int*   ri;
  u16*         cbf;      // bf16 output (EPI2/EPI4)
  int r0;
  int RC;
};

// C[m,n] = sum_k A[m,k]*B[n,k] (+bias[n]); A,B bf16 row-major. BM=BN=128, BK=32.
// 2-phase pipeline: global_load_lds stages tile kt+1 while MFMA consumes tile kt.
// EPI: 0 = f32 store; 1 = GRU finish (bf16 hidden); 2 = out-layer relu->bf16;
//      3 = fused z/rv sigmoids; 4 = bf16 store to cbf
template<int EPI>
__global__ __launch_bounds__(256)
void gemm_bf16(const u16* __restrict__ A, int lda,
               const u16* __restrict__ B, int ldb,
               const float* __restrict__ bias,
               float* __restrict__ C, int ldc, int K, EpiArgs e)
{
  __shared__ __align__(16) u16 As[2][128*32];
  __shared__ __align__(16) u16 Bs[2][128*32];
  const int tid = threadIdx.x;
  const int l   = tid & 63;
  const int w   = tid >> 6;          // wave id 0..3
  const int wm  = w >> 1, wn = w & 1;
  const int bm  = blockIdx.y*128, bn = blockIdx.x*128;
  const int lr  = l & 15, q = l >> 4;

  // staging: wave w covers rows [w*32, w*32+32); two 16-row loads each for A and B.
  const int srow = w*32 + (l >> 2);
  const int scol = (l & 3)*8;
  const u16* gA = A + (size_t)(bm + srow)*lda + scol;
  const u16* gB = B + (size_t)(bn + srow)*ldb + scol;
  const size_t a16 = (size_t)16*lda, b16 = (size_t)16*ldb;

  f32x4 acc[4][4] = {};
  const int NT = K >> 5;

  {
    const u16* ga = gA; const u16* gb = gB;
    GLL16(ga,       &As[0][(w*32     )*32]);
    GLL16(ga + a16, &As[0][(w*32 + 16)*32]);
    GLL16(gb,       &Bs[0][(w*32     )*32]);
    GLL16(gb + b16, &Bs[0][(w*32 + 16)*32]);
  }
  __syncthreads();
  int cur = 0;
  for (int kt = 0; kt < NT; ++kt){
    if (kt + 1 < NT){
      const u16* ga = gA + (size_t)(kt+1)*32;
      const u16* gb = gB + (size_t)(kt+1)*32;
      const int nb = cur ^ 1;
      GLL16(ga,       &As[nb][(w*32     )*32]);
      GLL16(ga + a16, &As[nb][(w*32 + 16)*32]);
      GLL16(gb,       &Bs[nb][(w*32     )*32]);
      GLL16(gb + b16, &Bs[nb][(w*32 + 16)*32]);
    }
    bf16x8 af[4], bfr[4];
#pragma unroll
    for (int i = 0; i < 4; ++i)
      af[i] = *(const bf16x8*)&As[cur][(wm*64 + i*16 + lr)*32 + q*8];
#pragma unroll
    for (int i = 0; i < 4; ++i)
      bfr[i] = *(const bf16x8*)&Bs[cur][(wn*64 + i*16 + lr)*32 + q*8];
#pragma unroll
    for (int mi = 0; mi < 4; ++mi)
#pragma unroll
      for (int ni = 0; ni < 4; ++ni)
        acc[mi][ni] = __builtin_amdgcn_mfma_f32_16x16x32_bf16(af[mi], bfr[ni], acc[mi][ni], 0, 0, 0);
    __syncthreads();   // drains vmcnt (next tile staged) + lgkm (reads done)
    cur ^= 1;
  }

#pragma unroll
  for (int mi = 0; mi < 4; ++mi){
#pragma unroll
    for (int ni = 0; ni < 4; ++ni){
#pragma unroll
      for (int i = 0; i < 4; ++i){
        const int m = bm + wm*64 + mi*16 + q*4 + i;   // row = (lane>>4)*4 + reg
        const int n = bn + wn*64 + ni*16 + lr;        // col = lane&15
        float val = acc[mi][ni][i];
        if (bias) val += bias[n];
        if (EPI == 0){
          C[(size_t)m*ldc + n] = val;
        } else if (EPI == 4){
          e.cbf[(size_t)m*ldc + n] = f2bf(val);
        } else if (EPI == 3){
          // val = flat@U3 + u3b ; z = sig(a*W3eff + b3 + val); rv = sig(a*W4eff + b4 + val)
          int r = m/NODE, t = m - r*NODE;
          float a; const u16* mrow;
          if (t < 2){ a = 1.0f; mrow = e.msW + (size_t)r*1536; }
          else { a = e.Arel[(size_t)(e.r0+r)*NREL + (t-2)]; mrow = e.msW + (size_t)(e.RC + r)*1536; }
          float z  = sigmoidf_(fmaf(a, bf2f(mrow[n]),       e.b3[n]) + val);
          float rv = sigmoidf_(fmaf(a, bf2f(mrow[512 + n]), e.b4[n]) + val);
          size_t idx = (size_t)m*H + n;
          float f = bf2f(e.hid_r[idx]);
          e.z_bf[idx]   = f2bf(z);
          e.rvf_bf[idx] = f2bf(rv*f);
        } else if (EPI == 1){
          // val = (rv*flat)@U5 + u5b ; hv = tanh(a*W5eff + b5 + val); h = (1-z)h + z*hv
          int r = m/NODE, t = m - r*NODE;
          float aw = (t < 2) ? bf2f(e.msW[(size_t)r*1536 + 1024 + n])
                             : e.Arel[(size_t)(e.r0+r)*NREL + (t-2)] * bf2f(e.msW[(size_t)(e.RC + r)*1536 + 1024 + n]);
          float hv = tanhf(aw + e.b2[n] + val);
          size_t idx = (size_t)m*H + n;
          float z = bf2f(e.z_bf[idx]);
          float f = bf2f(e.hid_r[idx]);
          e.hid_w[idx] = f2bf((1.0f - z)*f + z*hv);
        } else {
          // EPI 2: relu(flat@ow1 + inp@ow2 + out_b) -> bf16
          int r = m/NODE, t = m - r*NODE;
          int gr = e.r0 + r;
          const float* g = (t == 0) ? e.ofW2 + (size_t)e.ri[gr*3+1]*H
                         : (t == 1) ? e.ofW2 + (size_t)e.ri[gr*3+2]*H
                         :            e.vW2  + (size_t)gr*H;
          e.cbf[(size_t)m*H + n] = f2bf(fmaxf(val + g[n], 0.0f));
        }
      }
    }
  }
}

// classifier split-K: part[kz][m][n] = K-slice kz of A[m,:].B[n,:]
__global__ __launch_bounds__(64)
void cls_gemm(const u16* __restrict__ A, const u16* __restrict__ B,
              float* __restrict__ part, int RC)
{
  const int bm = blockIdx.x*64;
  const int kz = blockIdx.y;
  const int l  = threadIdx.x;
  const int lr = l & 15, q = l >> 4;
  f32x4 acc[4][4] = {};
  const size_t kbase = (size_t)kz*1696 + q*8;
  for (int kt = 0; kt < 53; ++kt){
    const size_t ko = kbase + (size_t)kt*32;
    bf16x8 af[4], bfr[4];
#pragma unroll
    for (int i = 0; i < 4; ++i)
      af[i] = *(const bf16x8*)&A[(size_t)(bm + i*16 + lr)*CLS_K + ko];
#pragma unroll
    for (int i = 0; i < 4; ++i)
      bfr[i] = *(const bf16x8*)&B[(size_t)(i*16 + lr)*CLS_K + ko];
#pragma unroll
    for (int mi = 0; mi < 4; ++mi)
#pragma unroll
      for (int ni = 0; ni < 4; ++ni)
        acc[mi][ni] = __builtin_amdgcn_mfma_f32_16x16x32_bf16(af[mi], bfr[ni], acc[mi][ni], 0, 0, 0);
  }
#pragma unroll
  for (int mi = 0; mi < 4; ++mi)
#pragma unroll
    for (int ni = 0; ni < 4; ++ni)
#pragma unroll
      for (int i = 0; i < 4; ++i){
        int m = bm + mi*16 + q*4 + i;
        int n = ni*16 + lr;
        part[((size_t)kz*RC + m)*64 + n] = acc[mi][ni][i];
      }
}

__global__ void cls_reduce(const float* __restrict__ part, const float* __restrict__ clsb,
                           float* __restrict__ rd, int r0, int RC)
{
  const int m = blockIdx.x;
  const int c = threadIdx.x;
  if (c < NREL){
    float s = clsb[c];
    for (int kz = 0; kz < 16; ++kz) s += part[((size_t)kz*RC + m)*64 + c];
    rd[(size_t)(r0 + m)*NREL + c] = s;
  }
}

__global__ void argmax_copy_kernel(const float* __restrict__ logits, float* __restrict__ out, int* __restrict__ preds)
{
  const int i = blockIdx.x;
  const int lane = threadIdx.x; // 64
  for (int c = lane; c < NCLS; c += 64)
    out[(size_t)i*NCLS + c] = logits[(size_t)i*NCLS + c];
  float bv = -INFINITY; int bi = 0x7fffffff;
  for (int c = 1 + lane; c < NCLS; c += 64){
    float x = logits[(size_t)i*NCLS + c];
    if (x > bv){ bv = x; bi = c; }
  }
  for (int off = 32; off; off >>= 1){
    float ov = __shfl_down(bv, off);
    int   oi = __shfl_down(bi, off);
    if (ov > bv || (ov == bv && oi < bi)){ bv = ov; bi = oi; }
  }
  if (lane == 0){
    preds[i] = bi;
    out[(size_t)N_OBJ*NCLS + i] = (float)bi;
  }
}

__global__ void conv_f2b(const float* __restrict__ s, u16* __restrict__ d, long n)
{
  for (long i = (long)blockIdx.x*blockDim.x + threadIdx.x; i < n; i += (long)gridDim.x*blockDim.x)
    d[i] = f2bf(s[i]);
}

__global__ void conv_ow(const float* __restrict__ src, u16* __restrict__ d1, u16* __restrict__ d2)
{
  for (int i = blockIdx.x*blockDim.x + threadIdx.x; i < 512*512; i += gridDim.x*blockDim.x){
    int r = i >> 9, c = i & 511;
    d1[i] = f2bf(src[(size_t)r*1024 + c]);
    d2[i] = f2bf(src[(size_t)r*1024 + 512 + c]);
  }
}

__global__ void conv_cls(const float* __restrict__ src, u16* __restrict__ dst)
{
  const long total = 64L*CLS_K;
  for (long i = (long)blockIdx.x*blockDim.x + threadIdx.x; i < total; i += (long)gridDim.x*blockDim.x){
    long r = i / CLS_K, c = i - r*CLS_K;
    dst[i] = (r < NREL) ? f2bf(src[(size_t)r*CLS_K + c]) : (u16)0;
  }
}

// Wcat rows [0:512)=W3eff, [512:1024)=W4eff, [1024:1536)=W5eff ; Weff = W[:,:512]+W[:,512:]
__global__ void wcat_kernel(const float* __restrict__ e3w, const float* __restrict__ e4w,
                            const float* __restrict__ e5w, u16* __restrict__ Wcat)
{
  const int total = 1536*512;
  for (int i = blockIdx.x*blockDim.x + threadIdx.x; i < total; i += gridDim.x*blockDim.x){
    int j = i >> 9, k = i & 511;
    int w = j >> 9, n = j & 511;
    const float* Wp = (w == 0) ? e3w : (w == 1) ? e4w : e5w;
    Wcat[i] = f2bf(Wp[(size_t)n*1024 + k] + Wp[(size_t)n*1024 + 512 + k]);
  }
}

__global__ void build_hidden_kernel(const u16* __restrict__ of, const u16* __restrict__ v,
                                    const int* __restrict__ ri, u16* __restrict__ hidden,
                                    int r0, int total8)
{
  for (int i = blockIdx.x*blockDim.x + threadIdx.x; i < total8; i += gridDim.x*blockDim.x){
    int h8 = i & 63;
    int m = i >> 6;
    int r = m/NODE, t = m - r*NODE;
    int gr = r0 + r;
    const u16* src = (t == 0) ? of + (size_t)ri[gr*3+1]*H
                   : (t == 1) ? of + (size_t)ri[gr*3+2]*H
                   :            v  + (size_t)gr*H;
    ((uint4*)hidden)[i] = ((const uint4*)src)[h8];
  }
}

__global__ void arel_kernel(const int* __restrict__ preds, const int* __restrict__ ri,
                            const float* __restrict__ prior, float* __restrict__ Arel)
{
  const int total = R_REL*NREL;
  for (int i = blockIdx.x*blockDim.x + threadIdx.x; i < total; i += gridDim.x*blockDim.x){
    int r = i/NREL, k = i - r*NREL;
    int sp = preds[ri[r*3+1]];
    int op = preds[ri[r*3+2]];
    Arel[i] = prior[((size_t)sp*NCLS + op)*NREL + k];
  }
}

// X rows [0:RC) = m_top (bf16), [RC:2RC) = h0+h1 (bf16)
__global__ void mtop_s_kernel(const u16* __restrict__ hidden, const float* __restrict__ Arel,
                              u16* __restrict__ X, int r0, int RC)
{
  const int r = blockIdx.x;
  for (int h = threadIdx.x; h < H; h += blockDim.x){
    const u16* basep = hidden + ((size_t)r*NODE + 2)*H + h;
    float acc = 0.f;
    for (int k = 0; k < NREL; ++k)
      acc = fmaf(Arel[(size_t)(r0+r)*NREL + k], bf2f(basep[(size_t)k*H]), acc);
    X[(size_t)r*H + h] = f2bf(acc);
    X[(size_t)(RC + r)*H + h] = f2bf(bf2f(hidden[(size_t)(r*NODE)*H + h]) + bf2f(hidden[(size_t)(r*NODE+1)*H + h]));
  }
}

extern "C" void kernel_launch(void* const* d_in, const int* in_sizes, int n_in,
                              void* d_out, int out_size, void* d_ws, size_t ws_size,
                              hipStream_t stream)
{
  const float* obj_fmaps = (const float*)d_in[0];
  const float* obj_logits= (const float*)d_in[1];
  const int*   rel_inds  = (const int*)d_in[2];
  const float* vr        = (const float*)d_in[3];
  const float* prior     = (const float*)d_in[4];
  const float* obj_proj_w= (const float*)d_in[5];
  const float* obj_proj_b= (const float*)d_in[6];
  const float* rel_proj_w= (const float*)d_in[7];
  const float* rel_proj_b= (const float*)d_in[8];
  const float* e3w =(const float*)d_in[9];
  const float* e3wb=(const float*)d_in[10];
  const float* e3u =(const float*)d_in[11];
  const float* e3ub=(const float*)d_in[12];
  const float* e4w =(const float*)d_in[13];
  const float* e4wb=(const float*)d_in[14];
  const float* e5w =(const float*)d_in[15];
  const float* e5wb=(const float*)d_in[16];
  const float* e5u =(const float*)d_in[17];
  const float* e5ub=(const float*)d_in[18];
  const float* outw=(const float*)d_in[19];
  const float* outbias=(const float*)d_in[20];
  const float* clsw=(const float*)d_in[21];
  const float* clsb=(const float*)d_in[22];
  float* out = (float*)d_out;
  (void)in_sizes; (void)n_in; (void)out_size;

  char* base = (char*)d_ws;
  size_t off = 0;
  auto take = [&](size_t bytes)->void*{
    void* p = base + off; off = (off + bytes + 63) & ~(size_t)63; return p;
  };
  // persistent (~31 MB)
  float* ofW2   = (float*)take((size_t)N_OBJ*H*4);
  float* vW2    = (float*)take((size_t)R_REL*H*4);
  float* Arel   = (float*)take((size_t)R_REL*NREL*4);
  int*   preds  = (int*)take((size_t)N_OBJ*4);
  u16* opw_bf   = (u16*)take((size_t)H*OBJ_DIM*2);
  u16* rpw_bf   = (u16*)take((size_t)H*OBJ_DIM*2);
  u16* e3u_bf   = (u16*)take((size_t)H*H*2);
  u16* e5u_bf   = (u16*)take((size_t)H*H*2);
  u16* ow1_bf   = (u16*)take((size_t)H*H*2);
  u16* ow2_bf   = (u16*)take((size_t)H*H*2);
  u16* wcat_bf  = (u16*)take((size_t)1536*H*2);
  u16* clsw_bf  = (u16*)take((size_t)64*CLS_K*2);
  u16* of_bf    = (u16*)take((size_t)N_OBJ*H*2);
  u16* v_bf     = (u16*)take((size_t)R_REL*H*2);
  const size_t mark = off;

  // union region: bf16 input copies (dead before chunk loop starts)
  u16* fmaps_bf = (u16*)(base + mark);
  u16* vr_bf    = fmaps_bf + (size_t)N_OBJ*OBJ_DIM;
  const size_t unionA = ((size_t)N_OBJ*OBJ_DIM + (size_t)R_REL*OBJ_DIM)*2;

  auto perbytes = [&](size_t rc)->size_t{
    return rc*((size_t)NODE*H*2*3     // hid_bf, z_bf, rvf_bf
             + 2*1536*2               // msW bf16
             + 16*64*4                // cls partials
             + 2*H*2)                 // X bf16
           + 1024;
  };
  int RC = 1024;
  while (RC > 64){
    size_t per = perbytes((size_t)RC);
    size_t need = mark + (per > unionA ? per : unionA);
    if (need <= ws_size) break;
    RC >>= 1;
  }
  const int NCH = R_REL / RC;
  const int M_c = RC*NODE;
  const int total8 = M_c*(H/8);

  off = mark;
  u16* hid_bf    = (u16*)take((size_t)M_c*H*2);
  u16* z_bf      = (u16*)take((size_t)M_c*H*2);
  u16* rvf_bf    = (u16*)take((size_t)M_c*H*2);
  u16* msW_bf    = (u16*)take((size_t)2*RC*1536*2);
  u16* X_bf      = (u16*)take((size_t)2*RC*H*2);
  float* clspart = (float*)take((size_t)16*RC*64*4);

  EpiArgs e0{};

  argmax_copy_kernel<<<N_OBJ, 64, 0, stream>>>(obj_logits, out, preds);

  conv_f2b<<<2048, 256, 0, stream>>>(obj_fmaps, fmaps_bf, (long)N_OBJ*OBJ_DIM);
  conv_f2b<<<2048, 256, 0, stream>>>(vr, vr_bf, (long)R_REL*OBJ_DIM);
  conv_f2b<<<1024, 256, 0, stream>>>(obj_proj_w, opw_bf, (long)H*OBJ_DIM);
  conv_f2b<<<1024, 256, 0, stream>>>(rel_proj_w, rpw_bf, (long)H*OBJ_DIM);
  conv_f2b<<<256, 256, 0, stream>>>(e3u, e3u_bf, (long)H*H);
  conv_f2b<<<256, 256, 0, stream>>>(e5u, e5u_bf, (long)H*H);
  conv_ow<<<256, 256, 0, stream>>>(outw, ow1_bf, ow2_bf);
  conv_cls<<<2048, 256, 0, stream>>>(clsw, clsw_bf);
  wcat_kernel<<<768, 256, 0, stream>>>(e3w, e4w, e5w, wcat_bf);
  arel_kernel<<<204, 256, 0, stream>>>(preds, rel_inds, prior, Arel);

  // projections -> bf16 of/v
  { EpiArgs e = e0; e.cbf = of_bf;
    gemm_bf16<4><<<dim3(H/128, N_OBJ/128), 256, 0, stream>>>(fmaps_bf, OBJ_DIM, opw_bf, OBJ_DIM, obj_proj_b, nullptr, H, OBJ_DIM, e); }
  { EpiArgs e = e0; e.cbf = v_bf;
    gemm_bf16<4><<<dim3(H/128, R_REL/128), 256, 0, stream>>>(vr_bf, OBJ_DIM, rpw_bf, OBJ_DIM, rel_proj_b, nullptr, H, OBJ_DIM, e); }

  // loop-invariant out-layer inp-part projections (f32, gathered in EPI2)
  gemm_bf16<0><<<dim3(H/128, N_OBJ/128), 256, 0, stream>>>(of_bf, H, ow2_bf, H, nullptr, ofW2, H, H, e0);
  gemm_bf16<0><<<dim3(H/128, R_REL/128), 256, 0, stream>>>(v_bf, H, ow2_bf, H, nullptr, vW2, H, H, e0);

  float* rd = out + (size_t)N_OBJ*NCLS + N_OBJ;

  for (int c = 0; c < NCH; ++c){
    const int r0 = c*RC;
    build_hidden_kernel<<<2048, 256, 0, stream>>>(of_bf, v_bf, rel_inds, hid_bf, r0, total8);

    for (int step = 0; step < 3; ++step){
      mtop_s_kernel<<<RC, 256, 0, stream>>>(hid_bf, Arel, X_bf, r0, RC);
      { EpiArgs e = e0; e.cbf = msW_bf;
        gemm_bf16<4><<<dim3(1536/128, 2*RC/128), 256, 0, stream>>>(X_bf, H, wcat_bf, H, nullptr, nullptr, 1536, H, e); }
      { EpiArgs e = e0;
        e.msW = msW_bf; e.Arel = Arel; e.b3 = e3wb; e.b4 = e4wb;
        e.hid_r = hid_bf; e.z_bf = z_bf; e.rvf_bf = rvf_bf; e.r0 = r0; e.RC = RC;
        gemm_bf16<3><<<dim3(H/128, M_c/128), 256, 0, stream>>>(hid_bf, H, e3u_bf, H, e3ub, nullptr, 0, H, e); }
      { EpiArgs e = e0;
        e.msW = msW_bf; e.Arel = Arel; e.b2 = e5wb; e.z_bf = z_bf;
        e.hid_r = hid_bf; e.hid_w = hid_bf; e.r0 = r0; e.RC = RC;
        gemm_bf16<1><<<dim3(H/128, M_c/128), 256, 0, stream>>>(rvf_bf, H, e5u_bf, H, e5ub, nullptr, 0, H, e); }
    }

    { EpiArgs e = e0;
      e.ofW2 = ofW2; e.vW2 = vW2; e.ri = rel_inds; e.cbf = rvf_bf; e.r0 = r0; e.RC = RC;
      gemm_bf16<2><<<dim3(H/128, M_c/128), 256, 0, stream>>>(hid_bf, H, ow1_bf, H, outbias, nullptr, 0, H, e); }

    cls_gemm<<<dim3(RC/64, 16), 64, 0, stream>>>(rvf_bf, clsw_bf, clspart, RC);
    cls_reduce<<<RC, 64, 0, stream>>>(clspart, clsb, rd, r0, RC);
  }
}